// Round 5
// baseline (1011.144 us; speedup 1.0000x reference)
//
#include <hip/hip_runtime.h>
#include <hip/hip_bf16.h>

// Problem constants
#define BROWS 16384
#define NDIM  2048
#define NCLS  100

typedef __attribute__((ext_vector_type(8))) __bf16 bf16x8;
typedef __attribute__((ext_vector_type(4))) float f32x4;
typedef __attribute__((ext_vector_type(16))) float f32x16;
typedef __attribute__((ext_vector_type(4))) unsigned short u16x4;
typedef __attribute__((ext_vector_type(8))) unsigned short u16x8;

__device__ __forceinline__ unsigned short f2bf(float f) {
    union { float f; unsigned int u; } v; v.f = f;
    unsigned int u = v.u;
    unsigned int r = (u + 0x7fffu + ((u >> 16) & 1u)) >> 16;   // RNE
    return (unsigned short)r;
}
__device__ __forceinline__ float bf2f(unsigned short h) {
    union { unsigned int u; float f; } v; v.u = ((unsigned int)h) << 16;
    return v.f;
}

#define GLOAD_LDS(g, l) \
    __builtin_amdgcn_global_load_lds((const __attribute__((address_space(1))) void*)(g), \
                                     (__attribute__((address_space(3))) void*)(l), 16, 0, 0)

// s_waitcnt immediates (gfx9 encoding: vmcnt[3:0]@0, expcnt@4, lgkmcnt@8, vmcnt[5:4]@14)
#define WAITCNT_VM4 0x0F74   // vmcnt(4), expcnt/lgkmcnt unrestricted

// ---------------------------------------------------------------------------
// prep: split x and w into (hi,lo) bf16 pairs in one launch.
// ---------------------------------------------------------------------------
__global__ __launch_bounds__(256) void prep_kernel(const float4* __restrict__ x,
                                                   const float4* __restrict__ w,
                                                   u16x4* __restrict__ xhi, u16x4* __restrict__ xlo,
                                                   u16x4* __restrict__ whi, u16x4* __restrict__ wlo,
                                                   int n4x, int n4w)
{
    int i = blockIdx.x * 256 + threadIdx.x;
    const float4* src; u16x4 *hi, *lo; int idx;
    if (i < n4x) { src = x; hi = xhi; lo = xlo; idx = i; }
    else { idx = i - n4x; if (idx >= n4w) return; src = w; hi = whi; lo = wlo; }
    float4 v = src[idx];
    u16x4 h, l;
    h.x = f2bf(v.x); l.x = f2bf(v.x - bf2f(h.x));
    h.y = f2bf(v.y); l.y = f2bf(v.y - bf2f(h.y));
    h.z = f2bf(v.z); l.z = f2bf(v.z - bf2f(h.z));
    h.w = f2bf(v.w); l.w = f2bf(v.w - bf2f(h.w));
    hi[idx] = h; lo[idx] = l;
}

// fp32 -> bf16 (hi only), for fc_weight (runs after gemm1; dst aliases wlo)
__global__ __launch_bounds__(256) void cvt_bf16_kernel(const float4* __restrict__ src,
                                                       u16x4* __restrict__ dst, int n4)
{
    int i = blockIdx.x * 256 + threadIdx.x;
    if (i >= n4) return;
    float4 v = src[i];
    u16x4 h;
    h.x = f2bf(v.x); h.y = f2bf(v.y); h.z = f2bf(v.z); h.w = f2bf(v.w);
    dst[i] = h;
}

// ---------------------------------------------------------------------------
// GEMM1 (MFMA 32x32x16, split-bf16, fused, SOFTWARE-PIPELINED):
//   C = Xhi.Whi + Xhi.Wlo + Xlo.Whi + bias
// 128x128 tile, BK=16, 3-stage LDS pipeline (48 KB), raw s_waitcnt vmcnt(4)
// + s_barrier: tile k+1/k+2 loads stay in flight across the barrier (no
// vmcnt(0) drain). Chunk-major LDS [q][r]: frag ds_read_b128 is stride-16B
// over consecutive rows -> min-bound, no bank conflicts.
// Per iter/wave: 4 global_load_lds + 1 barrier + 8 ds_read_b128 + 12 MFMA.
// ---------------------------------------------------------------------------
__global__ __launch_bounds__(256) void gemm1_pipe_kernel(
        const unsigned short* __restrict__ xhi,
        const unsigned short* __restrict__ xlo,
        const unsigned short* __restrict__ whi,
        const unsigned short* __restrict__ wlo,
        const float* __restrict__ bias,
        float* __restrict__ C)
{
    // [stage][chunk-major tile: (q*128 + r) 16B chunks] ; 4 KB per stage-tile
    __shared__ unsigned short sAh[3 * 2048];
    __shared__ unsigned short sAl[3 * 2048];
    __shared__ unsigned short sBh[3 * 2048];
    __shared__ unsigned short sBl[3 * 2048];

    const int tid  = threadIdx.x;
    const int lane = tid & 63;
    const int w    = tid >> 6;
    const int wm   = w & 1;
    const int wn   = w >> 1;
    const int m0   = blockIdx.y * 128;
    const int n0   = blockIdx.x * 128;

    // staging: tile = 256 chunks (q in {0,1}, r in 0..127), 1 chunk/thread
    // chunk c = w*64+lane -> q = c>>7, r = c&127 ; LDS linear offset = c*8 shorts
    const int cc = w * 64 + lane;
    const int sq = cc >> 7;
    const int sr = cc & 127;
    const size_t a_goff = (size_t)(m0 + sr) * NDIM + sq * 8;
    const size_t b_goff = (size_t)(n0 + sr) * NDIM + sq * 8;
    const int lds_off = w * 512;   // wave-uniform (shorts)

    // fragment read offsets: A-frag (32x32x16): row = wm*64+i*32+(lane&31),
    // k-half q = lane>>5 -> chunk (q*128 + row), 8 shorts each
    const int ln32 = lane & 31;
    const int lk2  = lane >> 5;
    const int offA0 = (lk2 * 128 + wm * 64 +  0 + ln32) * 8;
    const int offA1 = (lk2 * 128 + wm * 64 + 32 + ln32) * 8;
    const int offB0 = (lk2 * 128 + wn * 64 +  0 + ln32) * 8;
    const int offB1 = (lk2 * 128 + wn * 64 + 32 + ln32) * 8;

    f32x16 acc[2][2];
#pragma unroll
    for (int i = 0; i < 2; i++)
#pragma unroll
        for (int j = 0; j < 2; j++)
#pragma unroll
            for (int r = 0; r < 16; r++) acc[i][j][r] = 0.f;

    // prologue: tiles 0,1 -> stages 0,1 (8 loads in flight)
    GLOAD_LDS(xhi + a_goff +  0, &sAh[lds_off]);
    GLOAD_LDS(xlo + a_goff +  0, &sAl[lds_off]);
    GLOAD_LDS(whi + b_goff +  0, &sBh[lds_off]);
    GLOAD_LDS(wlo + b_goff +  0, &sBl[lds_off]);
    GLOAD_LDS(xhi + a_goff + 16, &sAh[2048 + lds_off]);
    GLOAD_LDS(xlo + a_goff + 16, &sAl[2048 + lds_off]);
    GLOAD_LDS(whi + b_goff + 16, &sBh[2048 + lds_off]);
    GLOAD_LDS(wlo + b_goff + 16, &sBl[2048 + lds_off]);

    int st = 0;   // stage holding tile k
    int sn = 2;   // stage for tile k+2
    for (int k = 0; k < 128; ++k) {
        // wait: own tile-k loads done (k+1, k+2-issued-below stay in flight)
        __builtin_amdgcn_s_waitcnt(WAITCNT_VM4);
        __builtin_amdgcn_s_barrier();

        // issue tile k+2 into stage sn (after barrier: reorder-robust).
        // (k+2)&127 wraps at the end -> harmless redundant loads, uniform vmcnt.
        {
            const int kn = ((k + 2) & 127) * 16;
            const int so = sn * 2048 + lds_off;
            GLOAD_LDS(xhi + a_goff + kn, &sAh[so]);
            GLOAD_LDS(xlo + a_goff + kn, &sAl[so]);
            GLOAD_LDS(whi + b_goff + kn, &sBh[so]);
            GLOAD_LDS(wlo + b_goff + kn, &sBl[so]);
        }

        const int sb = st * 2048;
        bf16x8 ah[2], al[2], bh[2], bl[2];
        ah[0] = *(const bf16x8*)&sAh[sb + offA0];
        ah[1] = *(const bf16x8*)&sAh[sb + offA1];
        al[0] = *(const bf16x8*)&sAl[sb + offA0];
        al[1] = *(const bf16x8*)&sAl[sb + offA1];
        bh[0] = *(const bf16x8*)&sBh[sb + offB0];
        bh[1] = *(const bf16x8*)&sBh[sb + offB1];
        bl[0] = *(const bf16x8*)&sBl[sb + offB0];
        bl[1] = *(const bf16x8*)&sBl[sb + offB1];

#pragma unroll
        for (int i = 0; i < 2; i++)
#pragma unroll
            for (int j = 0; j < 2; j++) {
                acc[i][j] = __builtin_amdgcn_mfma_f32_32x32x16_bf16(ah[i], bh[j], acc[i][j], 0, 0, 0);
                acc[i][j] = __builtin_amdgcn_mfma_f32_32x32x16_bf16(ah[i], bl[j], acc[i][j], 0, 0, 0);
                acc[i][j] = __builtin_amdgcn_mfma_f32_32x32x16_bf16(al[i], bh[j], acc[i][j], 0, 0, 0);
            }

        st = (st == 2) ? 0 : st + 1;
        sn = (sn == 2) ? 0 : sn + 1;
    }

    // epilogue: 32x32 C/D: col = lane&31, row = (reg&3)+8*(reg>>2)+4*(lane>>5)
    float bb[2];
#pragma unroll
    for (int j = 0; j < 2; j++) bb[j] = bias[n0 + wn * 64 + j * 32 + ln32];
#pragma unroll
    for (int i = 0; i < 2; i++) {
#pragma unroll
        for (int j = 0; j < 2; j++) {
            const int n = n0 + wn * 64 + j * 32 + ln32;
#pragma unroll
            for (int reg = 0; reg < 16; reg++) {
                const int m = m0 + wm * 64 + i * 32 + (reg & 3) + 8 * (reg >> 2) + 4 * lk2;
                C[(size_t)m * NDIM + n] = acc[i][j][reg] + bb[j];
            }
        }
    }
}

// ---------------------------------------------------------------------------
// Warp kernel: gamma = cumsum(softmax(row)); warped = interp(gamma, xs, x_row)
// Writes warped as bf16.
// ---------------------------------------------------------------------------
__global__ __launch_bounds__(256) void warp_bf16_kernel(const float* __restrict__ X,
                                                        const float* __restrict__ L,
                                                        unsigned short* __restrict__ Wout)
{
    const int N = NDIM;
    const int row = blockIdx.x;
    const int tid = threadIdx.x;
    const int lane = tid & 63;
    const int wave = tid >> 6;

    __shared__ float s_x[NDIM];
    __shared__ float s_red[4];
    __shared__ float s_wsum[4];

    const float* lrow = L + (size_t)row * N;
    const float* xrow = X + (size_t)row * N;

    float v[8];
    {
        float4 l0 = *(const float4*)(lrow + tid * 8);
        float4 l1 = *(const float4*)(lrow + tid * 8 + 4);
        v[0] = l0.x; v[1] = l0.y; v[2] = l0.z; v[3] = l0.w;
        v[4] = l1.x; v[5] = l1.y; v[6] = l1.z; v[7] = l1.w;
        float4 x0 = *(const float4*)(xrow + tid * 8);
        float4 x1 = *(const float4*)(xrow + tid * 8 + 4);
        *(float4*)&s_x[tid * 8]     = x0;
        *(float4*)&s_x[tid * 8 + 4] = x1;
    }

    float mx = v[0];
#pragma unroll
    for (int j = 1; j < 8; j++) mx = fmaxf(mx, v[j]);
#pragma unroll
    for (int off = 32; off > 0; off >>= 1) mx = fmaxf(mx, __shfl_down(mx, off));
    if (lane == 0) s_red[wave] = mx;
    __syncthreads();
    mx = fmaxf(fmaxf(s_red[0], s_red[1]), fmaxf(s_red[2], s_red[3]));

    float c = 0.0f;
#pragma unroll
    for (int j = 0; j < 8; j++) {
        float e = __expf(v[j] - mx);
        c += e;
        v[j] = c;
    }

    float sc = c;
#pragma unroll
    for (int off = 1; off < 64; off <<= 1) {
        float t = __shfl_up(sc, off);
        if (lane >= off) sc += t;
    }
    if (lane == 63) s_wsum[wave] = sc;
    __syncthreads();
    float base = 0.0f, total = 0.0f;
#pragma unroll
    for (int w = 0; w < 4; w++) {
        float t = s_wsum[w];
        if (w < wave) base += t;
        total += t;
    }
    const float inv = 1.0f / total;
    const float prefix = base + (sc - c);

    u16x8 o;
#pragma unroll
    for (int j = 0; j < 8; j++) {
        float g = (prefix + v[j]) * inv;
        float pos = g * (float)(N - 1);
        pos = fminf(fmaxf(pos, 0.0f), (float)(N - 1));
        int i = (int)pos;
        if (i > N - 2) i = N - 2;
        float f = pos - (float)i;
        o[j] = f2bf(fmaf(f, s_x[i + 1] - s_x[i], s_x[i]));
    }
    *(u16x8*)(Wout + (size_t)row * N + tid * 8) = o;
}

// ---------------------------------------------------------------------------
// GEMM2 (MFMA bf16, R3-proven): out[m][n] = sum_k Wp[m][k]*F[n][k] + fb[n]
// BM=64, BN=128 (rows>=100 clamped), BK=32, 4 waves 2x2, 256 blocks.
// ---------------------------------------------------------------------------
__global__ __launch_bounds__(256) void gemm2_mfma_kernel(
        const unsigned short* __restrict__ Wp,   // warped bf16 [16384][2048]
        const unsigned short* __restrict__ F,    // fc bf16 [100][2048]
        const float* __restrict__ fb,
        float* __restrict__ out)
{
    __shared__ unsigned short sA[64 * 32];    // 4 KB
    __shared__ unsigned short sB[128 * 32];   // 8 KB

    const int tid  = threadIdx.x;
    const int lane = tid & 63;
    const int w    = tid >> 6;
    const int wm   = w & 1;    // 2 m-halves of 32
    const int wn   = w >> 1;   // 2 n-halves of 64
    const int m0   = blockIdx.x * 64;

    const int ca = w * 64 + lane;
    const int ra = ca >> 2;
    const int qa = (ca & 3) ^ ((ra >> 1) & 3);
    const size_t a_goff = (size_t)(m0 + ra) * NDIM + qa * 8;
    unsigned short* ldsA = &sA[w * 512];

    const int cb0 = w * 128 + lane;
    const int rb0 = cb0 >> 2;
    const int qb0 = (cb0 & 3) ^ ((rb0 >> 1) & 3);
    const int cb1 = cb0 + 64;
    const int rb1 = cb1 >> 2;
    const int qb1 = (cb1 & 3) ^ ((rb1 >> 1) & 3);
    const size_t b_goff0 = (size_t)(rb0 < NCLS ? rb0 : NCLS - 1) * NDIM + qb0 * 8;
    const size_t b_goff1 = (size_t)(rb1 < NCLS ? rb1 : NCLS - 1) * NDIM + qb1 * 8;
    unsigned short* ldsB0 = &sB[w * 1024];
    unsigned short* ldsB1 = &sB[w * 1024 + 512];

    const int lm = lane & 15;
    const int lk = lane >> 4;
    int offA[2], offB[4];
#pragma unroll
    for (int i = 0; i < 2; i++) {
        int r = wm * 32 + i * 16 + lm;
        offA[i] = r * 32 + ((lk ^ ((r >> 1) & 3)) * 8);
    }
#pragma unroll
    for (int j = 0; j < 4; j++) {
        int r = wn * 64 + j * 16 + lm;
        offB[j] = r * 32 + ((lk ^ ((r >> 1) & 3)) * 8);
    }

    f32x4 acc[2][4];
#pragma unroll
    for (int i = 0; i < 2; i++)
#pragma unroll
        for (int j = 0; j < 4; j++) acc[i][j] = (f32x4){0.f, 0.f, 0.f, 0.f};

    for (int kt = 0; kt < NDIM; kt += 32) {
        GLOAD_LDS(Wp + a_goff + kt, ldsA);
        GLOAD_LDS(F + b_goff0 + kt, ldsB0);
        GLOAD_LDS(F + b_goff1 + kt, ldsB1);
        __syncthreads();

        bf16x8 af[2], bf[4];
#pragma unroll
        for (int i = 0; i < 2; i++) af[i] = *(const bf16x8*)&sA[offA[i]];
#pragma unroll
        for (int j = 0; j < 4; j++) bf[j] = *(const bf16x8*)&sB[offB[j]];
#pragma unroll
        for (int i = 0; i < 2; i++)
#pragma unroll
            for (int j = 0; j < 4; j++)
                acc[i][j] = __builtin_amdgcn_mfma_f32_16x16x32_bf16(af[i], bf[j], acc[i][j], 0, 0, 0);
        __syncthreads();
    }

    const int cn = lane & 15;
    const int rg = lane >> 4;
#pragma unroll
    for (int i = 0; i < 2; i++) {
#pragma unroll
        for (int j = 0; j < 4; j++) {
            const int n = wn * 64 + j * 16 + cn;
            if (n < NCLS) {
                const float bbn = fb[n];
#pragma unroll
                for (int reg = 0; reg < 4; reg++) {
                    const int m = m0 + wm * 32 + i * 16 + rg * 4 + reg;
                    out[(size_t)m * NCLS + n] = acc[i][j][reg] + bbn;
                }
            }
        }
    }
}

// ---------------------------------------------------------------------------
// fp32 fallback path (only if ws_size too small) — proven R1 kernels.
// ---------------------------------------------------------------------------
__global__ __launch_bounds__(256) void gemm1_kernel(const float* __restrict__ X,
                                                    const float* __restrict__ W,
                                                    const float* __restrict__ bias,
                                                    float* __restrict__ C)
{
    const int K = NDIM;
    __shared__ float sA[16][128];
    __shared__ float sB[16][128];
    const int tid = threadIdx.x;
    const int tx = tid & 15;
    const int ty = tid >> 4;
    const int m0 = blockIdx.y * 128;
    const int n0 = blockIdx.x * 128;
    float acc[8][8];
#pragma unroll
    for (int i = 0; i < 8; i++)
#pragma unroll
        for (int j = 0; j < 8; j++) acc[i][j] = 0.0f;
    const int s_m = tid >> 1;
    const int s_c = (tid & 1) * 8;
    const float* Ag = X + (size_t)(m0 + s_m) * K + s_c;
    const float* Bg = W + (size_t)(n0 + s_m) * K + s_c;
    for (int kt = 0; kt < K; kt += 16) {
        float4 av0 = *(const float4*)(Ag + kt);
        float4 av1 = *(const float4*)(Ag + kt + 4);
        float4 bv0 = *(const float4*)(Bg + kt);
        float4 bv1 = *(const float4*)(Bg + kt + 4);
        __syncthreads();
        sA[s_c + 0][s_m] = av0.x; sA[s_c + 1][s_m] = av0.y;
        sA[s_c + 2][s_m] = av0.z; sA[s_c + 3][s_m] = av0.w;
        sA[s_c + 4][s_m] = av1.x; sA[s_c + 5][s_m] = av1.y;
        sA[s_c + 6][s_m] = av1.z; sA[s_c + 7][s_m] = av1.w;
        sB[s_c + 0][s_m] = bv0.x; sB[s_c + 1][s_m] = bv0.y;
        sB[s_c + 2][s_m] = bv0.z; sB[s_c + 3][s_m] = bv0.w;
        sB[s_c + 4][s_m] = bv1.x; sB[s_c + 5][s_m] = bv1.y;
        sB[s_c + 6][s_m] = bv1.z; sB[s_c + 7][s_m] = bv1.w;
        __syncthreads();
#pragma unroll
        for (int k = 0; k < 16; k++) {
            float4 a0 = *(const float4*)&sA[k][ty * 8];
            float4 a1 = *(const float4*)&sA[k][ty * 8 + 4];
            float4 b0 = *(const float4*)&sB[k][tx * 8];
            float4 b1 = *(const float4*)&sB[k][tx * 8 + 4];
            float a[8] = {a0.x, a0.y, a0.z, a0.w, a1.x, a1.y, a1.z, a1.w};
            float b[8] = {b0.x, b0.y, b0.z, b0.w, b1.x, b1.y, b1.z, b1.w};
#pragma unroll
            for (int i = 0; i < 8; i++)
#pragma unroll
                for (int j = 0; j < 8; j++)
                    acc[i][j] = fmaf(a[i], b[j], acc[i][j]);
        }
    }
    float bb[8];
#pragma unroll
    for (int j = 0; j < 8; j++) bb[j] = bias[n0 + tx * 8 + j];
#pragma unroll
    for (int i = 0; i < 8; i++) {
        const int m = m0 + ty * 8 + i;
        float* crow = C + (size_t)m * NDIM + n0 + tx * 8;
        *(float4*)(crow)     = make_float4(acc[i][0] + bb[0], acc[i][1] + bb[1],
                                           acc[i][2] + bb[2], acc[i][3] + bb[3]);
        *(float4*)(crow + 4) = make_float4(acc[i][4] + bb[4], acc[i][5] + bb[5],
                                           acc[i][6] + bb[6], acc[i][7] + bb[7]);
    }
}

__global__ __launch_bounds__(256) void warp_kernel_f32(const float* __restrict__ X,
                                                       float* __restrict__ L)
{
    const int N = NDIM;
    const int row = blockIdx.x;
    const int tid = threadIdx.x;
    const int lane = tid & 63;
    const int wave = tid >> 6;
    __shared__ float s_x[NDIM];
    __shared__ float s_red[4];
    __shared__ float s_wsum[4];
    float* lrow = L + (size_t)row * N;
    const float* xrow = X + (size_t)row * N;
    float v[8];
    {
        float4 l0 = *(const float4*)(lrow + tid * 8);
        float4 l1 = *(const float4*)(lrow + tid * 8 + 4);
        v[0] = l0.x; v[1] = l0.y; v[2] = l0.z; v[3] = l0.w;
        v[4] = l1.x; v[5] = l1.y; v[6] = l1.z; v[7] = l1.w;
        float4 x0 = *(const float4*)(xrow + tid * 8);
        float4 x1 = *(const float4*)(xrow + tid * 8 + 4);
        *(float4*)&s_x[tid * 8]     = x0;
        *(float4*)&s_x[tid * 8 + 4] = x1;
    }
    float mx = v[0];
#pragma unroll
    for (int j = 1; j < 8; j++) mx = fmaxf(mx, v[j]);
#pragma unroll
    for (int off = 32; off > 0; off >>= 1) mx = fmaxf(mx, __shfl_down(mx, off));
    if (lane == 0) s_red[wave] = mx;
    __syncthreads();
    mx = fmaxf(fmaxf(s_red[0], s_red[1]), fmaxf(s_red[2], s_red[3]));
    float c = 0.0f;
#pragma unroll
    for (int j = 0; j < 8; j++) {
        float e = __expf(v[j] - mx);
        c += e;
        v[j] = c;
    }
    float sc = c;
#pragma unroll
    for (int off = 1; off < 64; off <<= 1) {
        float t = __shfl_up(sc, off);
        if (lane >= off) sc += t;
    }
    if (lane == 63) s_wsum[wave] = sc;
    __syncthreads();
    float base = 0.0f, total = 0.0f;
#pragma unroll
    for (int w = 0; w < 4; w++) {
        float t = s_wsum[w];
        if (w < wave) base += t;
        total += t;
    }
    const float inv = 1.0f / total;
    const float prefix = base + (sc - c);
    float w8[8];
#pragma unroll
    for (int j = 0; j < 8; j++) {
        float g = (prefix + v[j]) * inv;
        float pos = g * (float)(N - 1);
        pos = fminf(fmaxf(pos, 0.0f), (float)(N - 1));
        int i = (int)pos;
        if (i > N - 2) i = N - 2;
        float f = pos - (float)i;
        w8[j] = fmaf(f, s_x[i + 1] - s_x[i], s_x[i]);
    }
    *(float4*)(lrow + tid * 8)     = make_float4(w8[0], w8[1], w8[2], w8[3]);
    *(float4*)(lrow + tid * 8 + 4) = make_float4(w8[4], w8[5], w8[6], w8[7]);
}

__global__ __launch_bounds__(256) void gemm2_kernel(const float* __restrict__ Wp,
                                                    const float* __restrict__ F,
                                                    const float* __restrict__ fb,
                                                    float* __restrict__ out)
{
    const int K = NDIM;
    __shared__ float sA[16][64];
    __shared__ float sB[16][128];
    const int tid = threadIdx.x;
    const int tx = tid & 15;
    const int ty = tid >> 4;
    const int m0 = blockIdx.x * 64;
    float acc[4][8];
#pragma unroll
    for (int i = 0; i < 4; i++)
#pragma unroll
        for (int j = 0; j < 8; j++) acc[i][j] = 0.0f;
    const int a_m = tid >> 2;
    const int a_c = (tid & 3) * 4;
    const int b_n = tid >> 1;
    const int b_c = (tid & 1) * 8;
    const bool bvalid = (b_n < NCLS);
    const float* Ag = Wp + (size_t)(m0 + a_m) * K + a_c;
    const float* Bg = F + (size_t)b_n * K + b_c;
    for (int kt = 0; kt < K; kt += 16) {
        float4 av = *(const float4*)(Ag + kt);
        float4 bv0 = make_float4(0.f, 0.f, 0.f, 0.f);
        float4 bv1 = make_float4(0.f, 0.f, 0.f, 0.f);
        if (bvalid) {
            bv0 = *(const float4*)(Bg + kt);
            bv1 = *(const float4*)(Bg + kt + 4);
        }
        __syncthreads();
        sA[a_c + 0][a_m] = av.x; sA[a_c + 1][a_m] = av.y;
        sA[a_c + 2][a_m] = av.z; sA[a_c + 3][a_m] = av.w;
        sB[b_c + 0][b_n] = bv0.x; sB[b_c + 1][b_n] = bv0.y;
        sB[b_c + 2][b_n] = bv0.z; sB[b_c + 3][b_n] = bv0.w;
        sB[b_c + 4][b_n] = bv1.x; sB[b_c + 5][b_n] = bv1.y;
        sB[b_c + 6][b_n] = bv1.z; sB[b_c + 7][b_n] = bv1.w;
        __syncthreads();
#pragma unroll
        for (int k = 0; k < 16; k++) {
            float4 a4 = *(const float4*)&sA[k][ty * 4];
            float4 b0 = *(const float4*)&sB[k][tx * 8];
            float4 b1 = *(const float4*)&sB[k][tx * 8 + 4];
            float a[4] = {a4.x, a4.y, a4.z, a4.w};
            float b[8] = {b0.x, b0.y, b0.z, b0.w, b1.x, b1.y, b1.z, b1.w};
#pragma unroll
            for (int i = 0; i < 4; i++)
#pragma unroll
                for (int j = 0; j < 8; j++)
                    acc[i][j] = fmaf(a[i], b[j], acc[i][j]);
        }
    }
#pragma unroll
    for (int i = 0; i < 4; i++) {
        const int m = m0 + ty * 4 + i;
#pragma unroll
        for (int j = 0; j < 8; j++) {
            const int n = tx * 8 + j;
            if (n < NCLS) out[(size_t)m * NCLS + n] = acc[i][j] + fb[n];
        }
    }
}

extern "C" void kernel_launch(void* const* d_in, const int* in_sizes, int n_in,
                              void* d_out, int out_size, void* d_ws, size_t ws_size,
                              hipStream_t stream) {
    const float* x  = (const float*)d_in[0];   // time_series [16384,2048]
    const float* ww = (const float*)d_in[1];   // w_weight [2048,2048]
    const float* wb = (const float*)d_in[2];   // w_bias [2048]
    const float* fw = (const float*)d_in[3];   // fc_weight [100,2048]
    const float* fb = (const float*)d_in[4];   // fc_bias [100]
    float* out = (float*)d_out;                // [16384,100]

    char* ws = (char*)d_ws;
    float* logits = (float*)ws;                                   // 128 MiB fp32
    const size_t LOGITS_B = (size_t)BROWS * NDIM * 4;             // 134217728
    const size_t XBF_B    = (size_t)BROWS * NDIM * 2;             // 67108864
    const size_t WBF_B    = (size_t)NDIM * NDIM * 2;              // 8388608
    unsigned short* xhi = (unsigned short*)(ws + LOGITS_B);
    unsigned short* xlo = (unsigned short*)(ws + LOGITS_B + XBF_B);
    unsigned short* whi = (unsigned short*)(ws + LOGITS_B + 2 * XBF_B);
    unsigned short* wlo = (unsigned short*)(ws + LOGITS_B + 2 * XBF_B + WBF_B);
    // aliases (dead after gemm1): warped bf16 reuses xlo; fc bf16 reuses wlo
    unsigned short* wbf = xlo;
    unsigned short* fwb = wlo;
    const size_t WS_NEED = LOGITS_B + 2 * XBF_B + 2 * WBF_B;      // 285212672

    if (ws_size >= WS_NEED) {
        const int n4x = BROWS * NDIM / 4;   // 8388608
        const int n4w = NDIM * NDIM / 4;    // 1048576
        prep_kernel<<<(n4x + n4w + 255) / 256, 256, 0, stream>>>(
            (const float4*)x, (const float4*)ww,
            (u16x4*)xhi, (u16x4*)xlo, (u16x4*)whi, (u16x4*)wlo, n4x, n4w);
        gemm1_pipe_kernel<<<dim3(NDIM / 128, BROWS / 128), 256, 0, stream>>>(
            xhi, xlo, whi, wlo, wb, logits);
        warp_bf16_kernel<<<BROWS, 256, 0, stream>>>(x, logits, wbf);
        cvt_bf16_kernel<<<(NCLS * NDIM / 4 + 255) / 256, 256, 0, stream>>>(
            (const float4*)fw, (u16x4*)fwb, NCLS * NDIM / 4);
        gemm2_mfma_kernel<<<BROWS / 64, 256, 0, stream>>>(wbf, fwb, fb, out);
    } else {
        gemm1_kernel<<<dim3(NDIM / 128, BROWS / 128), 256, 0, stream>>>(x, ww, wb, logits);
        warp_kernel_f32<<<BROWS, 256, 0, stream>>>(x, logits);
        gemm2_kernel<<<BROWS / 64, 256, 0, stream>>>(logits, fw, fb, out);
    }
}

// Round 6
// 887.510 us; speedup vs baseline: 1.1393x; 1.1393x over previous
//
#include <hip/hip_runtime.h>
#include <hip/hip_bf16.h>

// Problem constants
#define BROWS 16384
#define NDIM  2048
#define NCLS  100

typedef __attribute__((ext_vector_type(8))) __bf16 bf16x8;
typedef __attribute__((ext_vector_type(4))) float f32x4;
typedef __attribute__((ext_vector_type(16))) float f32x16;
typedef __attribute__((ext_vector_type(4))) unsigned short u16x4;
typedef __attribute__((ext_vector_type(8))) unsigned short u16x8;

__device__ __forceinline__ unsigned short f2bf(float f) {
    union { float f; unsigned int u; } v; v.f = f;
    unsigned int u = v.u;
    unsigned int r = (u + 0x7fffu + ((u >> 16) & 1u)) >> 16;   // RNE
    return (unsigned short)r;
}
__device__ __forceinline__ float bf2f(unsigned short h) {
    union { unsigned int u; float f; } v; v.u = ((unsigned int)h) << 16;
    return v.f;
}

#define GLOAD_LDS(g, l) \
    __builtin_amdgcn_global_load_lds((const __attribute__((address_space(1))) void*)(g), \
                                     (__attribute__((address_space(3))) void*)(l), 16, 0, 0)

// ---------------------------------------------------------------------------
// prep: split x and w into (hi,lo) bf16 pairs in one launch.
// ---------------------------------------------------------------------------
__global__ __launch_bounds__(256) void prep_kernel(const float4* __restrict__ x,
                                                   const float4* __restrict__ w,
                                                   u16x4* __restrict__ xhi, u16x4* __restrict__ xlo,
                                                   u16x4* __restrict__ whi, u16x4* __restrict__ wlo,
                                                   int n4x, int n4w)
{
    int i = blockIdx.x * 256 + threadIdx.x;
    const float4* src; u16x4 *hi, *lo; int idx;
    if (i < n4x) { src = x; hi = xhi; lo = xlo; idx = i; }
    else { idx = i - n4x; if (idx >= n4w) return; src = w; hi = whi; lo = wlo; }
    float4 v = src[idx];
    u16x4 h, l;
    h.x = f2bf(v.x); l.x = f2bf(v.x - bf2f(h.x));
    h.y = f2bf(v.y); l.y = f2bf(v.y - bf2f(h.y));
    h.z = f2bf(v.z); l.z = f2bf(v.z - bf2f(h.z));
    h.w = f2bf(v.w); l.w = f2bf(v.w - bf2f(h.w));
    hi[idx] = h; lo[idx] = l;
}

// fp32 -> bf16 (hi only), for fc_weight (runs after gemm1; dst aliases wlo)
__global__ __launch_bounds__(256) void cvt_bf16_kernel(const float4* __restrict__ src,
                                                       u16x4* __restrict__ dst, int n4)
{
    int i = blockIdx.x * 256 + threadIdx.x;
    if (i >= n4) return;
    float4 v = src[i];
    u16x4 h;
    h.x = f2bf(v.x); h.y = f2bf(v.y); h.z = f2bf(v.z); h.w = f2bf(v.w);
    dst[i] = h;
}

// ---------------------------------------------------------------------------
// GEMM1 (MFMA 32x32x16, split-bf16, fused): C = Xhi.Whi + Xhi.Wlo + Xlo.Whi + b
// R4's 2-barrier BK=32 loop (24 MFMA per barrier-pair) + R5's conflict-free
// CHUNK-MAJOR LDS: linear chunk = q*128 + r (q = k-chunk 0..3, r = row 0..127).
// Frag ds_read_b128 runs over consecutive rows (consecutive 16B) -> 0 bank
// conflicts (R5-measured). Staging is 16B/row scattered -> L2 absorbs
// (R5-measured: FETCH_SIZE unchanged vs 64B-contiguous staging).
// ---------------------------------------------------------------------------
__global__ __launch_bounds__(256) void gemm1_mfma_fused_kernel(
        const unsigned short* __restrict__ xhi,
        const unsigned short* __restrict__ xlo,
        const unsigned short* __restrict__ whi,
        const unsigned short* __restrict__ wlo,
        const float* __restrict__ bias,
        float* __restrict__ C)
{
    __shared__ unsigned short sAh[4096];   // 8 KB each, chunk-major [q][r]
    __shared__ unsigned short sAl[4096];
    __shared__ unsigned short sBh[4096];
    __shared__ unsigned short sBl[4096];

    const int tid  = threadIdx.x;
    const int lane = tid & 63;
    const int w    = tid >> 6;
    const int wm   = w & 1;
    const int wn   = w >> 1;
    const int m0   = blockIdx.y * 128;
    const int n0   = blockIdx.x * 128;

    // staging: 512 chunks/tile (16B each), 2 per thread: c0 = tid, c1 = tid+256
    const int c0 = w * 64 + lane;
    const int q0 = c0 >> 7, r0 = c0 & 127;    // q0 in {0,1}
    const int c1 = c0 + 256;
    const int q1 = c1 >> 7, r1 = c1 & 127;    // q1 in {2,3}

    const size_t a_goff0 = (size_t)(m0 + r0) * NDIM + q0 * 8;
    const size_t a_goff1 = (size_t)(m0 + r1) * NDIM + q1 * 8;
    const size_t b_goff0 = (size_t)(n0 + r0) * NDIM + q0 * 8;
    const size_t b_goff1 = (size_t)(n0 + r1) * NDIM + q1 * 8;

    const int lb0 = w * 512;          // wave-uniform LDS base (shorts), chunk c0
    const int lb1 = 2048 + w * 512;   // chunk c1

    // fragment offsets: A-frag row ra = wm*64+i*32+(lane&31), k-chunk q = 2*ks+lk2
    const int ln32 = lane & 31;
    const int lk2  = lane >> 5;
    int offA[2][2], offB[2][2];   // [tile i][kstep]
#pragma unroll
    for (int i = 0; i < 2; i++)
#pragma unroll
        for (int ks = 0; ks < 2; ks++) {
            offA[i][ks] = ((2 * ks + lk2) * 128 + wm * 64 + i * 32 + ln32) * 8;
            offB[i][ks] = ((2 * ks + lk2) * 128 + wn * 64 + i * 32 + ln32) * 8;
        }

    f32x16 acc[2][2];
#pragma unroll
    for (int i = 0; i < 2; i++)
#pragma unroll
        for (int j = 0; j < 2; j++)
#pragma unroll
            for (int r = 0; r < 16; r++) acc[i][j][r] = 0.f;

    for (int kt = 0; kt < NDIM; kt += 32) {
        GLOAD_LDS(xhi + a_goff0 + kt, &sAh[lb0]);
        GLOAD_LDS(xhi + a_goff1 + kt, &sAh[lb1]);
        GLOAD_LDS(xlo + a_goff0 + kt, &sAl[lb0]);
        GLOAD_LDS(xlo + a_goff1 + kt, &sAl[lb1]);
        GLOAD_LDS(whi + b_goff0 + kt, &sBh[lb0]);
        GLOAD_LDS(whi + b_goff1 + kt, &sBh[lb1]);
        GLOAD_LDS(wlo + b_goff0 + kt, &sBl[lb0]);
        GLOAD_LDS(wlo + b_goff1 + kt, &sBl[lb1]);
        __syncthreads();

#pragma unroll
        for (int ks = 0; ks < 2; ks++) {
            bf16x8 ah[2], al[2], bh[2], bl[2];
#pragma unroll
            for (int i = 0; i < 2; i++) {
                ah[i] = *(const bf16x8*)&sAh[offA[i][ks]];
                al[i] = *(const bf16x8*)&sAl[offA[i][ks]];
                bh[i] = *(const bf16x8*)&sBh[offB[i][ks]];
                bl[i] = *(const bf16x8*)&sBl[offB[i][ks]];
            }
#pragma unroll
            for (int i = 0; i < 2; i++)
#pragma unroll
                for (int j = 0; j < 2; j++) {
                    acc[i][j] = __builtin_amdgcn_mfma_f32_32x32x16_bf16(ah[i], bh[j], acc[i][j], 0, 0, 0);
                    acc[i][j] = __builtin_amdgcn_mfma_f32_32x32x16_bf16(ah[i], bl[j], acc[i][j], 0, 0, 0);
                    acc[i][j] = __builtin_amdgcn_mfma_f32_32x32x16_bf16(al[i], bh[j], acc[i][j], 0, 0, 0);
                }
        }
        __syncthreads();
    }

    // epilogue: 32x32 C/D: col = lane&31, row = (reg&3)+8*(reg>>2)+4*(lane>>5)
    float bb[2];
#pragma unroll
    for (int j = 0; j < 2; j++) bb[j] = bias[n0 + wn * 64 + j * 32 + ln32];
#pragma unroll
    for (int i = 0; i < 2; i++) {
#pragma unroll
        for (int j = 0; j < 2; j++) {
            const int n = n0 + wn * 64 + j * 32 + ln32;
#pragma unroll
            for (int reg = 0; reg < 16; reg++) {
                const int m = m0 + wm * 64 + i * 32 + (reg & 3) + 8 * (reg >> 2) + 4 * lk2;
                C[(size_t)m * NDIM + n] = acc[i][j][reg] + bb[j];
            }
        }
    }
}

// ---------------------------------------------------------------------------
// Warp kernel: gamma = cumsum(softmax(row)); warped = interp(gamma, xs, x_row)
// Writes warped as bf16. s_x uses padded index i+(i>>5) to break the 16-way
// bank conflict on the interp gather (pos ~ element index -> lanes hit only
// 4 distinct banks unpadded).
// ---------------------------------------------------------------------------
#define SXI(i) ((i) + ((i) >> 5))

__global__ __launch_bounds__(256) void warp_bf16_kernel(const float* __restrict__ X,
                                                        const float* __restrict__ L,
                                                        unsigned short* __restrict__ Wout)
{
    const int N = NDIM;
    const int row = blockIdx.x;
    const int tid = threadIdx.x;
    const int lane = tid & 63;
    const int wave = tid >> 6;

    __shared__ float s_x[NDIM + NDIM / 32];   // padded: 1 extra per 32
    __shared__ float s_red[4];
    __shared__ float s_wsum[4];

    const float* lrow = L + (size_t)row * N;
    const float* xrow = X + (size_t)row * N;

    float v[8];
    {
        float4 l0 = *(const float4*)(lrow + tid * 8);
        float4 l1 = *(const float4*)(lrow + tid * 8 + 4);
        v[0] = l0.x; v[1] = l0.y; v[2] = l0.z; v[3] = l0.w;
        v[4] = l1.x; v[5] = l1.y; v[6] = l1.z; v[7] = l1.w;
        float4 x0 = *(const float4*)(xrow + tid * 8);
        float4 x1 = *(const float4*)(xrow + tid * 8 + 4);
        // all 8 indices tid*8..tid*8+7 share the same (i>>5) shift
        const int sb = SXI(tid * 8);
        *(float4*)&s_x[sb]     = x0;
        *(float4*)&s_x[sb + 4] = x1;
    }

    float mx = v[0];
#pragma unroll
    for (int j = 1; j < 8; j++) mx = fmaxf(mx, v[j]);
#pragma unroll
    for (int off = 32; off > 0; off >>= 1) mx = fmaxf(mx, __shfl_down(mx, off));
    if (lane == 0) s_red[wave] = mx;
    __syncthreads();
    mx = fmaxf(fmaxf(s_red[0], s_red[1]), fmaxf(s_red[2], s_red[3]));

    float c = 0.0f;
#pragma unroll
    for (int j = 0; j < 8; j++) {
        float e = __expf(v[j] - mx);
        c += e;
        v[j] = c;
    }

    float sc = c;
#pragma unroll
    for (int off = 1; off < 64; off <<= 1) {
        float t = __shfl_up(sc, off);
        if (lane >= off) sc += t;
    }
    if (lane == 63) s_wsum[wave] = sc;
    __syncthreads();
    float base = 0.0f, total = 0.0f;
#pragma unroll
    for (int w = 0; w < 4; w++) {
        float t = s_wsum[w];
        if (w < wave) base += t;
        total += t;
    }
    const float inv = 1.0f / total;
    const float prefix = base + (sc - c);

    u16x8 o;
#pragma unroll
    for (int j = 0; j < 8; j++) {
        float g = (prefix + v[j]) * inv;
        float pos = g * (float)(N - 1);
        pos = fminf(fmaxf(pos, 0.0f), (float)(N - 1));
        int i = (int)pos;
        if (i > N - 2) i = N - 2;
        float f = pos - (float)i;
        float x0 = s_x[SXI(i)];
        float x1 = s_x[SXI(i + 1)];
        o[j] = f2bf(fmaf(f, x1 - x0, x0));
    }
    *(u16x8*)(Wout + (size_t)row * N + tid * 8) = o;
}

// ---------------------------------------------------------------------------
// GEMM2 (MFMA bf16): out[m][n] = sum_k Wp[m][k]*F[n][k] + fb[n]  (n<100)
// BM=64, BN=128 (rows>=100 clamped), BK=64 (32 barriered iters), 4 waves 2x2,
// each wave 32m x 64n. Chunk-major LDS (conflict-free). 256 blocks.
// ---------------------------------------------------------------------------
__global__ __launch_bounds__(256) void gemm2_mfma_kernel(
        const unsigned short* __restrict__ Wp,   // warped bf16 [16384][2048]
        const unsigned short* __restrict__ F,    // fc bf16 [100][2048]
        const float* __restrict__ fb,
        float* __restrict__ out)
{
    __shared__ unsigned short sA[64 * 64];    // 8 KB, chunk-major [q0..7][r0..63]
    __shared__ unsigned short sB[128 * 64];   // 16 KB, chunk-major [q0..7][r0..127]

    const int tid  = threadIdx.x;
    const int lane = tid & 63;
    const int w    = tid >> 6;
    const int wm   = w & 1;    // 2 m-halves of 32
    const int wn   = w >> 1;   // 2 n-halves of 64
    const int m0   = blockIdx.x * 64;

    // A staging: 512 chunks, 2/thread
    size_t a_goff[2]; int a_lb[2];
#pragma unroll
    for (int t = 0; t < 2; t++) {
        const int c = t * 256 + w * 64 + lane;
        const int q = c >> 6, r = c & 63;
        a_goff[t] = (size_t)(m0 + r) * NDIM + q * 8;
        a_lb[t]   = (t * 256 + w * 64) * 8;   // wave-uniform (shorts)
    }
    // B staging: 1024 chunks, 4/thread; fc row clamped to 99
    size_t b_goff[4]; int b_lb[4];
#pragma unroll
    for (int t = 0; t < 4; t++) {
        const int c = t * 256 + w * 64 + lane;
        const int q = c >> 7, r = c & 127;
        b_goff[t] = (size_t)(r < NCLS ? r : NCLS - 1) * NDIM + q * 8;
        b_lb[t]   = (t * 256 + w * 64) * 8;
    }

    // fragment offsets (16x16x32): k-chunk = ks*4 + (lane>>4)
    const int lm = lane & 15;
    const int lk = lane >> 4;
    int offA[2][2], offB[4][2];
#pragma unroll
    for (int i = 0; i < 2; i++)
#pragma unroll
        for (int ks = 0; ks < 2; ks++)
            offA[i][ks] = ((ks * 4 + lk) * 64 + wm * 32 + i * 16 + lm) * 8;
#pragma unroll
    for (int j = 0; j < 4; j++)
#pragma unroll
        for (int ks = 0; ks < 2; ks++)
            offB[j][ks] = ((ks * 4 + lk) * 128 + wn * 64 + j * 16 + lm) * 8;

    f32x4 acc[2][4];
#pragma unroll
    for (int i = 0; i < 2; i++)
#pragma unroll
        for (int j = 0; j < 4; j++) acc[i][j] = (f32x4){0.f, 0.f, 0.f, 0.f};

    for (int kt = 0; kt < NDIM; kt += 64) {
#pragma unroll
        for (int t = 0; t < 2; t++) GLOAD_LDS(Wp + a_goff[t] + kt, &sA[a_lb[t]]);
#pragma unroll
        for (int t = 0; t < 4; t++) GLOAD_LDS(F + b_goff[t] + kt, &sB[b_lb[t]]);
        __syncthreads();

#pragma unroll
        for (int ks = 0; ks < 2; ks++) {
            bf16x8 af[2], bf[4];
#pragma unroll
            for (int i = 0; i < 2; i++) af[i] = *(const bf16x8*)&sA[offA[i][ks]];
#pragma unroll
            for (int j = 0; j < 4; j++) bf[j] = *(const bf16x8*)&sB[offB[j][ks]];
#pragma unroll
            for (int i = 0; i < 2; i++)
#pragma unroll
                for (int j = 0; j < 4; j++)
                    acc[i][j] = __builtin_amdgcn_mfma_f32_16x16x32_bf16(af[i], bf[j], acc[i][j], 0, 0, 0);
        }
        __syncthreads();
    }

    const int cn = lane & 15;
    const int rg = lane >> 4;
#pragma unroll
    for (int i = 0; i < 2; i++) {
#pragma unroll
        for (int j = 0; j < 4; j++) {
            const int n = wn * 64 + j * 16 + cn;
            if (n < NCLS) {
                const float bbn = fb[n];
#pragma unroll
                for (int reg = 0; reg < 4; reg++) {
                    const int m = m0 + wm * 32 + i * 16 + rg * 4 + reg;
                    out[(size_t)m * NCLS + n] = acc[i][j][reg] + bbn;
                }
            }
        }
    }
}

// ---------------------------------------------------------------------------
// fp32 fallback path (only if ws_size too small) — proven R1 kernels.
// ---------------------------------------------------------------------------
__global__ __launch_bounds__(256) void gemm1_kernel(const float* __restrict__ X,
                                                    const float* __restrict__ W,
                                                    const float* __restrict__ bias,
                                                    float* __restrict__ C)
{
    const int K = NDIM;
    __shared__ float sA[16][128];
    __shared__ float sB[16][128];
    const int tid = threadIdx.x;
    const int tx = tid & 15;
    const int ty = tid >> 4;
    const int m0 = blockIdx.y * 128;
    const int n0 = blockIdx.x * 128;
    float acc[8][8];
#pragma unroll
    for (int i = 0; i < 8; i++)
#pragma unroll
        for (int j = 0; j < 8; j++) acc[i][j] = 0.0f;
    const int s_m = tid >> 1;
    const int s_c = (tid & 1) * 8;
    const float* Ag = X + (size_t)(m0 + s_m) * K + s_c;
    const float* Bg = W + (size_t)(n0 + s_m) * K + s_c;
    for (int kt = 0; kt < K; kt += 16) {
        float4 av0 = *(const float4*)(Ag + kt);
        float4 av1 = *(const float4*)(Ag + kt + 4);
        float4 bv0 = *(const float4*)(Bg + kt);
        float4 bv1 = *(const float4*)(Bg + kt + 4);
        __syncthreads();
        sA[s_c + 0][s_m] = av0.x; sA[s_c + 1][s_m] = av0.y;
        sA[s_c + 2][s_m] = av0.z; sA[s_c + 3][s_m] = av0.w;
        sA[s_c + 4][s_m] = av1.x; sA[s_c + 5][s_m] = av1.y;
        sA[s_c + 6][s_m] = av1.z; sA[s_c + 7][s_m] = av1.w;
        sB[s_c + 0][s_m] = bv0.x; sB[s_c + 1][s_m] = bv0.y;
        sB[s_c + 2][s_m] = bv0.z; sB[s_c + 3][s_m] = bv0.w;
        sB[s_c + 4][s_m] = bv1.x; sB[s_c + 5][s_m] = bv1.y;
        sB[s_c + 6][s_m] = bv1.z; sB[s_c + 7][s_m] = bv1.w;
        __syncthreads();
#pragma unroll
        for (int k = 0; k < 16; k++) {
            float4 a0 = *(const float4*)&sA[k][ty * 8];
            float4 a1 = *(const float4*)&sA[k][ty * 8 + 4];
            float4 b0 = *(const float4*)&sB[k][tx * 8];
            float4 b1 = *(const float4*)&sB[k][tx * 8 + 4];
            float a[8] = {a0.x, a0.y, a0.z, a0.w, a1.x, a1.y, a1.z, a1.w};
            float b[8] = {b0.x, b0.y, b0.z, b0.w, b1.x, b1.y, b1.z, b1.w};
#pragma unroll
            for (int i = 0; i < 8; i++)
#pragma unroll
                for (int j = 0; j < 8; j++)
                    acc[i][j] = fmaf(a[i], b[j], acc[i][j]);
        }
    }
    float bb[8];
#pragma unroll
    for (int j = 0; j < 8; j++) bb[j] = bias[n0 + tx * 8 + j];
#pragma unroll
    for (int i = 0; i < 8; i++) {
        const int m = m0 + ty * 8 + i;
        float* crow = C + (size_t)m * NDIM + n0 + tx * 8;
        *(float4*)(crow)     = make_float4(acc[i][0] + bb[0], acc[i][1] + bb[1],
                                           acc[i][2] + bb[2], acc[i][3] + bb[3]);
        *(float4*)(crow + 4) = make_float4(acc[i][4] + bb[4], acc[i][5] + bb[5],
                                           acc[i][6] + bb[6], acc[i][7] + bb[7]);
    }
}

__global__ __launch_bounds__(256) void warp_kernel_f32(const float* __restrict__ X,
                                                       float* __restrict__ L)
{
    const int N = NDIM;
    const int row = blockIdx.x;
    const int tid = threadIdx.x;
    const int lane = tid & 63;
    const int wave = tid >> 6;
    __shared__ float s_x[NDIM];
    __shared__ float s_red[4];
    __shared__ float s_wsum[4];
    float* lrow = L + (size_t)row * N;
    const float* xrow = X + (size_t)row * N;
    float v[8];
    {
        float4 l0 = *(const float4*)(lrow + tid * 8);
        float4 l1 = *(const float4*)(lrow + tid * 8 + 4);
        v[0] = l0.x; v[1] = l0.y; v[2] = l0.z; v[3] = l0.w;
        v[4] = l1.x; v[5] = l1.y; v[6] = l1.z; v[7] = l1.w;
        float4 x0 = *(const float4*)(xrow + tid * 8);
        float4 x1 = *(const float4*)(xrow + tid * 8 + 4);
        *(float4*)&s_x[tid * 8]     = x0;
        *(float4*)&s_x[tid * 8 + 4] = x1;
    }
    float mx = v[0];
#pragma unroll
    for (int j = 1; j < 8; j++) mx = fmaxf(mx, v[j]);
#pragma unroll
    for (int off = 32; off > 0; off >>= 1) mx = fmaxf(mx, __shfl_down(mx, off));
    if (lane == 0) s_red[wave] = mx;
    __syncthreads();
    mx = fmaxf(fmaxf(s_red[0], s_red[1]), fmaxf(s_red[2], s_red[3]));
    float c = 0.0f;
#pragma unroll
    for (int j = 0; j < 8; j++) {
        float e = __expf(v[j] - mx);
        c += e;
        v[j] = c;
    }
    float sc = c;
#pragma unroll
    for (int off = 1; off < 64; off <<= 1) {
        float t = __shfl_up(sc, off);
        if (lane >= off) sc += t;
    }
    if (lane == 63) s_wsum[wave] = sc;
    __syncthreads();
    float base = 0.0f, total = 0.0f;
#pragma unroll
    for (int w = 0; w < 4; w++) {
        float t = s_wsum[w];
        if (w < wave) base += t;
        total += t;
    }
    const float inv = 1.0f / total;
    const float prefix = base + (sc - c);
    float w8[8];
#pragma unroll
    for (int j = 0; j < 8; j++) {
        float g = (prefix + v[j]) * inv;
        float pos = g * (float)(N - 1);
        pos = fminf(fmaxf(pos, 0.0f), (float)(N - 1));
        int i = (int)pos;
        if (i > N - 2) i = N - 2;
        float f = pos - (float)i;
        w8[j] = fmaf(f, s_x[i + 1] - s_x[i], s_x[i]);
    }
    *(float4*)(lrow + tid * 8)     = make_float4(w8[0], w8[1], w8[2], w8[3]);
    *(float4*)(lrow + tid * 8 + 4) = make_float4(w8[4], w8[5], w8[6], w8[7]);
}

__global__ __launch_bounds__(256) void gemm2_kernel(const float* __restrict__ Wp,
                                                    const float* __restrict__ F,
                                                    const float* __restrict__ fb,
                                                    float* __restrict__ out)
{
    const int K = NDIM;
    __shared__ float sA[16][64];
    __shared__ float sB[16][128];
    const int tid = threadIdx.x;
    const int tx = tid & 15;
    const int ty = tid >> 4;
    const int m0 = blockIdx.x * 64;
    float acc[4][8];
#pragma unroll
    for (int i = 0; i < 4; i++)
#pragma unroll
        for (int j = 0; j < 8; j++) acc[i][j] = 0.0f;
    const int a_m = tid >> 2;
    const int a_c = (tid & 3) * 4;
    const int b_n = tid >> 1;
    const int b_c = (tid & 1) * 8;
    const bool bvalid = (b_n < NCLS);
    const float* Ag = Wp + (size_t)(m0 + a_m) * K + a_c;
    const float* Bg = F + (size_t)b_n * K + b_c;
    for (int kt = 0; kt < K; kt += 16) {
        float4 av = *(const float4*)(Ag + kt);
        float4 bv0 = make_float4(0.f, 0.f, 0.f, 0.f);
        float4 bv1 = make_float4(0.f, 0.f, 0.f, 0.f);
        if (bvalid) {
            bv0 = *(const float4*)(Bg + kt);
            bv1 = *(const float4*)(Bg + kt + 4);
        }
        __syncthreads();
        sA[a_c + 0][a_m] = av.x; sA[a_c + 1][a_m] = av.y;
        sA[a_c + 2][a_m] = av.z; sA[a_c + 3][a_m] = av.w;
        sB[b_c + 0][b_n] = bv0.x; sB[b_c + 1][b_n] = bv0.y;
        sB[b_c + 2][b_n] = bv0.z; sB[b_c + 3][b_n] = bv0.w;
        sB[b_c + 4][b_n] = bv1.x; sB[b_c + 5][b_n] = bv1.y;
        sB[b_c + 6][b_n] = bv1.z; sB[b_c + 7][b_n] = bv1.w;
        __syncthreads();
#pragma unroll
        for (int k = 0; k < 16; k++) {
            float4 a4 = *(const float4*)&sA[k][ty * 4];
            float4 b0 = *(const float4*)&sB[k][tx * 8];
            float4 b1 = *(const float4*)&sB[k][tx * 8 + 4];
            float a[4] = {a4.x, a4.y, a4.z, a4.w};
            float b[8] = {b0.x, b0.y, b0.z, b0.w, b1.x, b1.y, b1.z, b1.w};
#pragma unroll
            for (int i = 0; i < 4; i++)
#pragma unroll
                for (int j = 0; j < 8; j++)
                    acc[i][j] = fmaf(a[i], b[j], acc[i][j]);
        }
    }
#pragma unroll
    for (int i = 0; i < 4; i++) {
        const int m = m0 + ty * 4 + i;
#pragma unroll
        for (int j = 0; j < 8; j++) {
            const int n = tx * 8 + j;
            if (n < NCLS) out[(size_t)m * NCLS + n] = acc[i][j] + fb[n];
        }
    }
}

extern "C" void kernel_launch(void* const* d_in, const int* in_sizes, int n_in,
                              void* d_out, int out_size, void* d_ws, size_t ws_size,
                              hipStream_t stream) {
    const float* x  = (const float*)d_in[0];   // time_series [16384,2048]
    const float* ww = (const float*)d_in[1];   // w_weight [2048,2048]
    const float* wb = (const float*)d_in[2];   // w_bias [2048]
    const float* fw = (const float*)d_in[3];   // fc_weight [100,2048]
    const float* fb = (const float*)d_in[4];   // fc_bias [100]
    float* out = (float*)d_out;                // [16384,100]

    char* ws = (char*)d_ws;
    float* logits = (float*)ws;                                   // 128 MiB fp32
    const size_t LOGITS_B = (size_t)BROWS * NDIM * 4;             // 134217728
    const size_t XBF_B    = (size_t)BROWS * NDIM * 2;             // 67108864
    const size_t WBF_B    = (size_t)NDIM * NDIM * 2;              // 8388608
    unsigned short* xhi = (unsigned short*)(ws + LOGITS_B);
    unsigned short* xlo = (unsigned short*)(ws + LOGITS_B + XBF_B);
    unsigned short* whi = (unsigned short*)(ws + LOGITS_B + 2 * XBF_B);
    unsigned short* wlo = (unsigned short*)(ws + LOGITS_B + 2 * XBF_B + WBF_B);
    // aliases (dead after gemm1): warped bf16 reuses xlo; fc bf16 reuses wlo
    unsigned short* wbf = xlo;
    unsigned short* fwb = wlo;
    const size_t WS_NEED = LOGITS_B + 2 * XBF_B + 2 * WBF_B;      // 285212672

    if (ws_size >= WS_NEED) {
        const int n4x = BROWS * NDIM / 4;   // 8388608
        const int n4w = NDIM * NDIM / 4;    // 1048576
        prep_kernel<<<(n4x + n4w + 255) / 256, 256, 0, stream>>>(
            (const float4*)x, (const float4*)ww,
            (u16x4*)xhi, (u16x4*)xlo, (u16x4*)whi, (u16x4*)wlo, n4x, n4w);
        gemm1_mfma_fused_kernel<<<dim3(NDIM / 128, BROWS / 128), 256, 0, stream>>>(
            xhi, xlo, whi, wlo, wb, logits);
        warp_bf16_kernel<<<BROWS, 256, 0, stream>>>(x, logits, wbf);
        cvt_bf16_kernel<<<(NCLS * NDIM / 4 + 255) / 256, 256, 0, stream>>>(
            (const float4*)fw, (u16x4*)fwb, NCLS * NDIM / 4);
        gemm2_mfma_kernel<<<BROWS / 64, 256, 0, stream>>>(wbf, fwb, fb, out);
    } else {
        gemm1_kernel<<<dim3(NDIM / 128, BROWS / 128), 256, 0, stream>>>(x, ww, wb, logits);
        warp_kernel_f32<<<BROWS, 256, 0, stream>>>(x, logits);
        gemm2_kernel<<<BROWS / 64, 256, 0, stream>>>(logits, fw, fb, out);
    }
}

// Round 7
// 686.687 us; speedup vs baseline: 1.4725x; 1.2925x over previous
//
#include <hip/hip_runtime.h>
#include <hip/hip_bf16.h>

// Problem constants
#define BROWS 16384
#define NDIM  2048
#define NCLS  100

typedef __attribute__((ext_vector_type(8))) __bf16 bf16x8;
typedef __attribute__((ext_vector_type(4))) float f32x4;
typedef __attribute__((ext_vector_type(16))) float f32x16;
typedef __attribute__((ext_vector_type(4))) unsigned short u16x4;
typedef __attribute__((ext_vector_type(8))) unsigned short u16x8;

__device__ __forceinline__ unsigned short f2bf(float f) {
    union { float f; unsigned int u; } v; v.f = f;
    unsigned int u = v.u;
    unsigned int r = (u + 0x7fffu + ((u >> 16) & 1u)) >> 16;   // RNE
    return (unsigned short)r;
}
__device__ __forceinline__ float bf2f(unsigned short h) {
    union { unsigned int u; float f; } v; v.u = ((unsigned int)h) << 16;
    return v.f;
}

#define GLOAD_LDS(g, l) \
    __builtin_amdgcn_global_load_lds((const __attribute__((address_space(1))) void*)(g), \
                                     (__attribute__((address_space(3))) void*)(l), 16, 0, 0)

// ---------------------------------------------------------------------------
// prep: split x and w into (hi,lo) bf16 pairs in one launch.
// ---------------------------------------------------------------------------
__global__ __launch_bounds__(256) void prep_kernel(const float4* __restrict__ x,
                                                   const float4* __restrict__ w,
                                                   u16x4* __restrict__ xhi, u16x4* __restrict__ xlo,
                                                   u16x4* __restrict__ whi, u16x4* __restrict__ wlo,
                                                   int n4x, int n4w)
{
    int i = blockIdx.x * 256 + threadIdx.x;
    const float4* src; u16x4 *hi, *lo; int idx;
    if (i < n4x) { src = x; hi = xhi; lo = xlo; idx = i; }
    else { idx = i - n4x; if (idx >= n4w) return; src = w; hi = whi; lo = wlo; }
    float4 v = src[idx];
    u16x4 h, l;
    h.x = f2bf(v.x); l.x = f2bf(v.x - bf2f(h.x));
    h.y = f2bf(v.y); l.y = f2bf(v.y - bf2f(h.y));
    h.z = f2bf(v.z); l.z = f2bf(v.z - bf2f(h.z));
    h.w = f2bf(v.w); l.w = f2bf(v.w - bf2f(h.w));
    hi[idx] = h; lo[idx] = l;
}

// fp32 -> bf16 (hi only), for fc_weight (runs after gemm1; dst aliases wlo)
__global__ __launch_bounds__(256) void cvt_bf16_kernel(const float4* __restrict__ src,
                                                       u16x4* __restrict__ dst, int n4)
{
    int i = blockIdx.x * 256 + threadIdx.x;
    if (i >= n4) return;
    float4 v = src[i];
    u16x4 h;
    h.x = f2bf(v.x); h.y = f2bf(v.y); h.z = f2bf(v.z); h.w = f2bf(v.w);
    dst[i] = h;
}

// ---------------------------------------------------------------------------
// GEMM1 (MFMA 32x32x16, split-bf16, fused) — R4 verbatim (403 us measured):
// C = Xhi.Whi + Xhi.Wlo + Xlo.Whi + bias.
// 128x128 tile, BK=32, row-major LDS [r][4 chunks] with XOR swizzle
// q ^= (r>>1)&3 (swizzle stays inside the 64B row segment -> staging fully
// coalesced; frag reads bank-uniform). 24 MFMA per barrier-pair.
// ---------------------------------------------------------------------------
__global__ __launch_bounds__(256) void gemm1_mfma_fused_kernel(
        const unsigned short* __restrict__ xhi,
        const unsigned short* __restrict__ xlo,
        const unsigned short* __restrict__ whi,
        const unsigned short* __restrict__ wlo,
        const float* __restrict__ bias,
        float* __restrict__ C)
{
    __shared__ unsigned short sAh[128 * 32];   // 8 KB each
    __shared__ unsigned short sAl[128 * 32];
    __shared__ unsigned short sBh[128 * 32];
    __shared__ unsigned short sBl[128 * 32];

    const int tid  = threadIdx.x;
    const int lane = tid & 63;
    const int w    = tid >> 6;
    const int wm   = w & 1;
    const int wn   = w >> 1;
    const int m0   = blockIdx.y * 128;
    const int n0   = blockIdx.x * 128;

    // staging: chunk = 16B = 8 bf16; tile = 512 chunks (128 rows x 4); 2/thread
    const int c0 = w * 128 + lane;
    const int r0 = c0 >> 2;
    const int q0 = (c0 & 3) ^ ((r0 >> 1) & 3);
    const int c1 = c0 + 64;
    const int r1 = c1 >> 2;
    const int q1 = (c1 & 3) ^ ((r1 >> 1) & 3);

    const size_t a_goff0 = (size_t)(m0 + r0) * NDIM + q0 * 8;
    const size_t a_goff1 = (size_t)(m0 + r1) * NDIM + q1 * 8;
    const size_t b_goff0 = (size_t)(n0 + r0) * NDIM + q0 * 8;
    const size_t b_goff1 = (size_t)(n0 + r1) * NDIM + q1 * 8;

    unsigned short* ldsAh0 = &sAh[w * 1024];   unsigned short* ldsAh1 = &sAh[w * 1024 + 512];
    unsigned short* ldsAl0 = &sAl[w * 1024];   unsigned short* ldsAl1 = &sAl[w * 1024 + 512];
    unsigned short* ldsBh0 = &sBh[w * 1024];   unsigned short* ldsBh1 = &sBh[w * 1024 + 512];
    unsigned short* ldsBl0 = &sBl[w * 1024];   unsigned short* ldsBl1 = &sBl[w * 1024 + 512];

    // fragment read offsets: frag row r, logical k-chunk q = 2*ks + lk2
    const int ln32 = lane & 31;
    const int lk2  = lane >> 5;
    int offA[2][2], offB[2][2];   // [tile i][kstep]
#pragma unroll
    for (int i = 0; i < 2; i++) {
#pragma unroll
        for (int ks = 0; ks < 2; ks++) {
            int ra = wm * 64 + i * 32 + ln32;
            offA[i][ks] = ra * 32 + (((2 * ks + lk2) ^ ((ra >> 1) & 3)) * 8);
            int rb = wn * 64 + i * 32 + ln32;
            offB[i][ks] = rb * 32 + (((2 * ks + lk2) ^ ((rb >> 1) & 3)) * 8);
        }
    }

    f32x16 acc[2][2];
#pragma unroll
    for (int i = 0; i < 2; i++)
#pragma unroll
        for (int j = 0; j < 2; j++)
#pragma unroll
            for (int r = 0; r < 16; r++) acc[i][j][r] = 0.f;

    for (int kt = 0; kt < NDIM; kt += 32) {
        GLOAD_LDS(xhi + a_goff0 + kt, ldsAh0);
        GLOAD_LDS(xhi + a_goff1 + kt, ldsAh1);
        GLOAD_LDS(xlo + a_goff0 + kt, ldsAl0);
        GLOAD_LDS(xlo + a_goff1 + kt, ldsAl1);
        GLOAD_LDS(whi + b_goff0 + kt, ldsBh0);
        GLOAD_LDS(whi + b_goff1 + kt, ldsBh1);
        GLOAD_LDS(wlo + b_goff0 + kt, ldsBl0);
        GLOAD_LDS(wlo + b_goff1 + kt, ldsBl1);
        __syncthreads();

#pragma unroll
        for (int ks = 0; ks < 2; ks++) {
            bf16x8 ah[2], al[2], bh[2], bl[2];
#pragma unroll
            for (int i = 0; i < 2; i++) {
                ah[i] = *(const bf16x8*)&sAh[offA[i][ks]];
                al[i] = *(const bf16x8*)&sAl[offA[i][ks]];
                bh[i] = *(const bf16x8*)&sBh[offB[i][ks]];
                bl[i] = *(const bf16x8*)&sBl[offB[i][ks]];
            }
#pragma unroll
            for (int i = 0; i < 2; i++)
#pragma unroll
                for (int j = 0; j < 2; j++) {
                    acc[i][j] = __builtin_amdgcn_mfma_f32_32x32x16_bf16(ah[i], bh[j], acc[i][j], 0, 0, 0);
                    acc[i][j] = __builtin_amdgcn_mfma_f32_32x32x16_bf16(ah[i], bl[j], acc[i][j], 0, 0, 0);
                    acc[i][j] = __builtin_amdgcn_mfma_f32_32x32x16_bf16(al[i], bh[j], acc[i][j], 0, 0, 0);
                }
        }
        __syncthreads();
    }

    // epilogue: 32x32 C/D: col = lane&31, row = (reg&3)+8*(reg>>2)+4*(lane>>5)
    float bb[2];
#pragma unroll
    for (int j = 0; j < 2; j++) bb[j] = bias[n0 + wn * 64 + j * 32 + ln32];
#pragma unroll
    for (int i = 0; i < 2; i++) {
#pragma unroll
        for (int j = 0; j < 2; j++) {
            const int n = n0 + wn * 64 + j * 32 + ln32;
#pragma unroll
            for (int reg = 0; reg < 16; reg++) {
                const int m = m0 + wm * 64 + i * 32 + (reg & 3) + 8 * (reg >> 2) + 4 * lk2;
                C[(size_t)m * NDIM + n] = acc[i][j][reg] + bb[j];
            }
        }
    }
}

// ---------------------------------------------------------------------------
// Warp kernel: gamma = cumsum(softmax(row)); warped = interp(gamma, xs, x_row)
// Reads x~ = xhi+xlo (bf16 pair, 64MB less HBM than fp32 x); padded s_x index
// i+(i>>5) breaks the interp-gather bank conflict. Writes warped bf16.
// Self-aliasing (Wout == xlo) is safe: each thread overwrites only its own
// loaded 16B; all gathers go through the LDS copy.
// ---------------------------------------------------------------------------
#define SXI(i) ((i) + ((i) >> 5))

__global__ __launch_bounds__(256) void warp_bf16_kernel(const unsigned short* __restrict__ Xhi,
                                                        const unsigned short* __restrict__ Xlo,
                                                        const float* __restrict__ L,
                                                        unsigned short* __restrict__ Wout)
{
    const int N = NDIM;
    const int row = blockIdx.x;
    const int tid = threadIdx.x;
    const int lane = tid & 63;
    const int wave = tid >> 6;

    __shared__ float s_x[NDIM + NDIM / 32];   // padded: 1 extra per 32
    __shared__ float s_red[4];
    __shared__ float s_wsum[4];

    const float* lrow = L + (size_t)row * N;

    float v[8];
    {
        float4 l0 = *(const float4*)(lrow + tid * 8);
        float4 l1 = *(const float4*)(lrow + tid * 8 + 4);
        v[0] = l0.x; v[1] = l0.y; v[2] = l0.z; v[3] = l0.w;
        v[4] = l1.x; v[5] = l1.y; v[6] = l1.z; v[7] = l1.w;
        u16x8 hx = *(const u16x8*)(Xhi + (size_t)row * N + tid * 8);
        u16x8 lx = *(const u16x8*)(Xlo + (size_t)row * N + tid * 8);
        float xv[8];
#pragma unroll
        for (int j = 0; j < 8; j++) xv[j] = bf2f(hx[j]) + bf2f(lx[j]);
        const int sb = SXI(tid * 8);   // 8 consecutive slots share the shift
        *(float4*)&s_x[sb]     = make_float4(xv[0], xv[1], xv[2], xv[3]);
        *(float4*)&s_x[sb + 4] = make_float4(xv[4], xv[5], xv[6], xv[7]);
    }

    float mx = v[0];
#pragma unroll
    for (int j = 1; j < 8; j++) mx = fmaxf(mx, v[j]);
#pragma unroll
    for (int off = 32; off > 0; off >>= 1) mx = fmaxf(mx, __shfl_down(mx, off));
    if (lane == 0) s_red[wave] = mx;
    __syncthreads();
    mx = fmaxf(fmaxf(s_red[0], s_red[1]), fmaxf(s_red[2], s_red[3]));

    float c = 0.0f;
#pragma unroll
    for (int j = 0; j < 8; j++) {
        float e = __expf(v[j] - mx);
        c += e;
        v[j] = c;
    }

    float sc = c;
#pragma unroll
    for (int off = 1; off < 64; off <<= 1) {
        float t = __shfl_up(sc, off);
        if (lane >= off) sc += t;
    }
    if (lane == 63) s_wsum[wave] = sc;
    __syncthreads();
    float base = 0.0f, total = 0.0f;
#pragma unroll
    for (int w = 0; w < 4; w++) {
        float t = s_wsum[w];
        if (w < wave) base += t;
        total += t;
    }
    const float inv = 1.0f / total;
    const float prefix = base + (sc - c);

    u16x8 o;
#pragma unroll
    for (int j = 0; j < 8; j++) {
        float g = (prefix + v[j]) * inv;
        float pos = g * (float)(N - 1);
        pos = fminf(fmaxf(pos, 0.0f), (float)(N - 1));
        int i = (int)pos;
        if (i > N - 2) i = N - 2;
        float f = pos - (float)i;
        float x0 = s_x[SXI(i)];
        float x1 = s_x[SXI(i + 1)];
        o[j] = f2bf(fmaf(f, x1 - x0, x0));
    }
    *(u16x8*)(Wout + (size_t)row * N + tid * 8) = o;
}

// ---------------------------------------------------------------------------
// GEMM2 (MFMA bf16): out[m][n] = sum_k Wp[m][k]*F[n][k] + fb[n]  (n<100)
// BM=64, BN=128 (rows>=100 clamped), BK=64 (32 barriered iters), 4 waves 2x2.
// Row-major LDS [r][8 chunks] + XOR swizzle q ^= r&7 (inside the 128B row
// segment -> staging coalesced; frag reads bank-uniform). 256 blocks.
// ---------------------------------------------------------------------------
__global__ __launch_bounds__(256) void gemm2_mfma_kernel(
        const unsigned short* __restrict__ Wp,   // warped bf16 [16384][2048]
        const unsigned short* __restrict__ F,    // fc bf16 [100][2048]
        const float* __restrict__ fb,
        float* __restrict__ out)
{
    __shared__ unsigned short sA[64 * 64];    // 8 KB, [r][q'] 8 chunks/row
    __shared__ unsigned short sB[128 * 64];   // 16 KB

    const int tid  = threadIdx.x;
    const int lane = tid & 63;
    const int w    = tid >> 6;
    const int wm   = w & 1;    // 2 m-halves of 32
    const int wn   = w >> 1;   // 2 n-halves of 64
    const int m0   = blockIdx.x * 64;

    // A staging: 512 chunks (64 rows x 8), 2/thread; lane order = r*8+q
    size_t a_goff[2]; int a_lb[2];
#pragma unroll
    for (int t = 0; t < 2; t++) {
        const int c = t * 256 + tid;
        const int r = c >> 3, q = c & 7;
        a_goff[t] = (size_t)(m0 + r) * NDIM + ((q ^ (r & 7)) * 8);
        a_lb[t]   = (t * 256 + w * 64) * 8;   // wave-uniform base (shorts)
    }
    // B staging: 1024 chunks (128 rows x 8), 4/thread; fc row clamped to 99
    size_t b_goff[4]; int b_lb[4];
#pragma unroll
    for (int t = 0; t < 4; t++) {
        const int c = t * 256 + tid;
        const int r = c >> 3, q = c & 7;
        b_goff[t] = (size_t)(r < NCLS ? r : NCLS - 1) * NDIM + ((q ^ (r & 7)) * 8);
        b_lb[t]   = (t * 256 + w * 64) * 8;
    }

    // fragment offsets (16x16x32): logical k-chunk = ks*4 + (lane>>4)
    const int lm = lane & 15;
    const int lk = lane >> 4;
    int offA[2][2], offB[4][2];
#pragma unroll
    for (int i = 0; i < 2; i++)
#pragma unroll
        for (int ks = 0; ks < 2; ks++) {
            const int r = wm * 32 + i * 16 + lm;
            offA[i][ks] = (r * 8 + ((ks * 4 + lk) ^ (r & 7))) * 8;
        }
#pragma unroll
    for (int j = 0; j < 4; j++)
#pragma unroll
        for (int ks = 0; ks < 2; ks++) {
            const int r = wn * 64 + j * 16 + lm;
            offB[j][ks] = (r * 8 + ((ks * 4 + lk) ^ (r & 7))) * 8;
        }

    f32x4 acc[2][4];
#pragma unroll
    for (int i = 0; i < 2; i++)
#pragma unroll
        for (int j = 0; j < 4; j++) acc[i][j] = (f32x4){0.f, 0.f, 0.f, 0.f};

    for (int kt = 0; kt < NDIM; kt += 64) {
#pragma unroll
        for (int t = 0; t < 2; t++) GLOAD_LDS(Wp + a_goff[t] + kt, &sA[a_lb[t]]);
#pragma unroll
        for (int t = 0; t < 4; t++) GLOAD_LDS(F + b_goff[t] + kt, &sB[b_lb[t]]);
        __syncthreads();

#pragma unroll
        for (int ks = 0; ks < 2; ks++) {
            bf16x8 af[2], bf[4];
#pragma unroll
            for (int i = 0; i < 2; i++) af[i] = *(const bf16x8*)&sA[offA[i][ks]];
#pragma unroll
            for (int j = 0; j < 4; j++) bf[j] = *(const bf16x8*)&sB[offB[j][ks]];
#pragma unroll
            for (int i = 0; i < 2; i++)
#pragma unroll
                for (int j = 0; j < 4; j++)
                    acc[i][j] = __builtin_amdgcn_mfma_f32_16x16x32_bf16(af[i], bf[j], acc[i][j], 0, 0, 0);
        }
        __syncthreads();
    }

    const int cn = lane & 15;
    const int rg = lane >> 4;
#pragma unroll
    for (int i = 0; i < 2; i++) {
#pragma unroll
        for (int j = 0; j < 4; j++) {
            const int n = wn * 64 + j * 16 + cn;
            if (n < NCLS) {
                const float bbn = fb[n];
#pragma unroll
                for (int reg = 0; reg < 4; reg++) {
                    const int m = m0 + wm * 32 + i * 16 + rg * 4 + reg;
                    out[(size_t)m * NCLS + n] = acc[i][j][reg] + bbn;
                }
            }
        }
    }
}

// ---------------------------------------------------------------------------
// fp32 fallback path (only if ws_size too small) — proven R1 kernels.
// ---------------------------------------------------------------------------
__global__ __launch_bounds__(256) void gemm1_kernel(const float* __restrict__ X,
                                                    const float* __restrict__ W,
                                                    const float* __restrict__ bias,
                                                    float* __restrict__ C)
{
    const int K = NDIM;
    __shared__ float sA[16][128];
    __shared__ float sB[16][128];
    const int tid = threadIdx.x;
    const int tx = tid & 15;
    const int ty = tid >> 4;
    const int m0 = blockIdx.y * 128;
    const int n0 = blockIdx.x * 128;
    float acc[8][8];
#pragma unroll
    for (int i = 0; i < 8; i++)
#pragma unroll
        for (int j = 0; j < 8; j++) acc[i][j] = 0.0f;
    const int s_m = tid >> 1;
    const int s_c = (tid & 1) * 8;
    const float* Ag = X + (size_t)(m0 + s_m) * K + s_c;
    const float* Bg = W + (size_t)(n0 + s_m) * K + s_c;
    for (int kt = 0; kt < K; kt += 16) {
        float4 av0 = *(const float4*)(Ag + kt);
        float4 av1 = *(const float4*)(Ag + kt + 4);
        float4 bv0 = *(const float4*)(Bg + kt);
        float4 bv1 = *(const float4*)(Bg + kt + 4);
        __syncthreads();
        sA[s_c + 0][s_m] = av0.x; sA[s_c + 1][s_m] = av0.y;
        sA[s_c + 2][s_m] = av0.z; sA[s_c + 3][s_m] = av0.w;
        sA[s_c + 4][s_m] = av1.x; sA[s_c + 5][s_m] = av1.y;
        sA[s_c + 6][s_m] = av1.z; sA[s_c + 7][s_m] = av1.w;
        sB[s_c + 0][s_m] = bv0.x; sB[s_c + 1][s_m] = bv0.y;
        sB[s_c + 2][s_m] = bv0.z; sB[s_c + 3][s_m] = bv0.w;
        sB[s_c + 4][s_m] = bv1.x; sB[s_c + 5][s_m] = bv1.y;
        sB[s_c + 6][s_m] = bv1.z; sB[s_c + 7][s_m] = bv1.w;
        __syncthreads();
#pragma unroll
        for (int k = 0; k < 16; k++) {
            float4 a0 = *(const float4*)&sA[k][ty * 8];
            float4 a1 = *(const float4*)&sA[k][ty * 8 + 4];
            float4 b0 = *(const float4*)&sB[k][tx * 8];
            float4 b1 = *(const float4*)&sB[k][tx * 8 + 4];
            float a[8] = {a0.x, a0.y, a0.z, a0.w, a1.x, a1.y, a1.z, a1.w};
            float b[8] = {b0.x, b0.y, b0.z, b0.w, b1.x, b1.y, b1.z, b1.w};
#pragma unroll
            for (int i = 0; i < 8; i++)
#pragma unroll
                for (int j = 0; j < 8; j++)
                    acc[i][j] = fmaf(a[i], b[j], acc[i][j]);
        }
    }
    float bb[8];
#pragma unroll
    for (int j = 0; j < 8; j++) bb[j] = bias[n0 + tx * 8 + j];
#pragma unroll
    for (int i = 0; i < 8; i++) {
        const int m = m0 + ty * 8 + i;
        float* crow = C + (size_t)m * NDIM + n0 + tx * 8;
        *(float4*)(crow)     = make_float4(acc[i][0] + bb[0], acc[i][1] + bb[1],
                                           acc[i][2] + bb[2], acc[i][3] + bb[3]);
        *(float4*)(crow + 4) = make_float4(acc[i][4] + bb[4], acc[i][5] + bb[5],
                                           acc[i][6] + bb[6], acc[i][7] + bb[7]);
    }
}

__global__ __launch_bounds__(256) void warp_kernel_f32(const float* __restrict__ X,
                                                       float* __restrict__ L)
{
    const int N = NDIM;
    const int row = blockIdx.x;
    const int tid = threadIdx.x;
    const int lane = tid & 63;
    const int wave = tid >> 6;
    __shared__ float s_x[NDIM];
    __shared__ float s_red[4];
    __shared__ float s_wsum[4];
    float* lrow = L + (size_t)row * N;
    const float* xrow = X + (size_t)row * N;
    float v[8];
    {
        float4 l0 = *(const float4*)(lrow + tid * 8);
        float4 l1 = *(const float4*)(lrow + tid * 8 + 4);
        v[0] = l0.x; v[1] = l0.y; v[2] = l0.z; v[3] = l0.w;
        v[4] = l1.x; v[5] = l1.y; v[6] = l1.z; v[7] = l1.w;
        float4 x0 = *(const float4*)(xrow + tid * 8);
        float4 x1 = *(const float4*)(xrow + tid * 8 + 4);
        *(float4*)&s_x[tid * 8]     = x0;
        *(float4*)&s_x[tid * 8 + 4] = x1;
    }
    float mx = v[0];
#pragma unroll
    for (int j = 1; j < 8; j++) mx = fmaxf(mx, v[j]);
#pragma unroll
    for (int off = 32; off > 0; off >>= 1) mx = fmaxf(mx, __shfl_down(mx, off));
    if (lane == 0) s_red[wave] = mx;
    __syncthreads();
    mx = fmaxf(fmaxf(s_red[0], s_red[1]), fmaxf(s_red[2], s_red[3]));
    float c = 0.0f;
#pragma unroll
    for (int j = 0; j < 8; j++) {
        float e = __expf(v[j] - mx);
        c += e;
        v[j] = c;
    }
    float sc = c;
#pragma unroll
    for (int off = 1; off < 64; off <<= 1) {
        float t = __shfl_up(sc, off);
        if (lane >= off) sc += t;
    }
    if (lane == 63) s_wsum[wave] = sc;
    __syncthreads();
    float base = 0.0f, total = 0.0f;
#pragma unroll
    for (int w = 0; w < 4; w++) {
        float t = s_wsum[w];
        if (w < wave) base += t;
        total += t;
    }
    const float inv = 1.0f / total;
    const float prefix = base + (sc - c);
    float w8[8];
#pragma unroll
    for (int j = 0; j < 8; j++) {
        float g = (prefix + v[j]) * inv;
        float pos = g * (float)(N - 1);
        pos = fminf(fmaxf(pos, 0.0f), (float)(N - 1));
        int i = (int)pos;
        if (i > N - 2) i = N - 2;
        float f = pos - (float)i;
        w8[j] = fmaf(f, s_x[i + 1] - s_x[i], s_x[i]);
    }
    *(float4*)(lrow + tid * 8)     = make_float4(w8[0], w8[1], w8[2], w8[3]);
    *(float4*)(lrow + tid * 8 + 4) = make_float4(w8[4], w8[5], w8[6], w8[7]);
}

__global__ __launch_bounds__(256) void gemm2_kernel(const float* __restrict__ Wp,
                                                    const float* __restrict__ F,
                                                    const float* __restrict__ fb,
                                                    float* __restrict__ out)
{
    const int K = NDIM;
    __shared__ float sA[16][64];
    __shared__ float sB[16][128];
    const int tid = threadIdx.x;
    const int tx = tid & 15;
    const int ty = tid >> 4;
    const int m0 = blockIdx.x * 64;
    float acc[4][8];
#pragma unroll
    for (int i = 0; i < 4; i++)
#pragma unroll
        for (int j = 0; j < 8; j++) acc[i][j] = 0.0f;
    const int a_m = tid >> 2;
    const int a_c = (tid & 3) * 4;
    const int b_n = tid >> 1;
    const int b_c = (tid & 1) * 8;
    const bool bvalid = (b_n < NCLS);
    const float* Ag = Wp + (size_t)(m0 + a_m) * K + a_c;
    const float* Bg = F + (size_t)b_n * K + b_c;
    for (int kt = 0; kt < K; kt += 16) {
        float4 av = *(const float4*)(Ag + kt);
        float4 bv0 = make_float4(0.f, 0.f, 0.f, 0.f);
        float4 bv1 = make_float4(0.f, 0.f, 0.f, 0.f);
        if (bvalid) {
            bv0 = *(const float4*)(Bg + kt);
            bv1 = *(const float4*)(Bg + kt + 4);
        }
        __syncthreads();
        sA[a_c + 0][a_m] = av.x; sA[a_c + 1][a_m] = av.y;
        sA[a_c + 2][a_m] = av.z; sA[a_c + 3][a_m] = av.w;
        sB[b_c + 0][b_n] = bv0.x; sB[b_c + 1][b_n] = bv0.y;
        sB[b_c + 2][b_n] = bv0.z; sB[b_c + 3][b_n] = bv0.w;
        sB[b_c + 4][b_n] = bv1.x; sB[b_c + 5][b_n] = bv1.y;
        sB[b_c + 6][b_n] = bv1.z; sB[b_c + 7][b_n] = bv1.w;
        __syncthreads();
#pragma unroll
        for (int k = 0; k < 16; k++) {
            float4 a4 = *(const float4*)&sA[k][ty * 4];
            float4 b0 = *(const float4*)&sB[k][tx * 8];
            float4 b1 = *(const float4*)&sB[k][tx * 8 + 4];
            float a[4] = {a4.x, a4.y, a4.z, a4.w};
            float b[8] = {b0.x, b0.y, b0.z, b0.w, b1.x, b1.y, b1.z, b1.w};
#pragma unroll
            for (int i = 0; i < 4; i++)
#pragma unroll
                for (int j = 0; j < 8; j++)
                    acc[i][j] = fmaf(a[i], b[j], acc[i][j]);
        }
    }
#pragma unroll
    for (int i = 0; i < 4; i++) {
        const int m = m0 + ty * 4 + i;
#pragma unroll
        for (int j = 0; j < 8; j++) {
            const int n = tx * 8 + j;
            if (n < NCLS) out[(size_t)m * NCLS + n] = acc[i][j] + fb[n];
        }
    }
}

extern "C" void kernel_launch(void* const* d_in, const int* in_sizes, int n_in,
                              void* d_out, int out_size, void* d_ws, size_t ws_size,
                              hipStream_t stream) {
    const float* x  = (const float*)d_in[0];   // time_series [16384,2048]
    const float* ww = (const float*)d_in[1];   // w_weight [2048,2048]
    const float* wb = (const float*)d_in[2];   // w_bias [2048]
    const float* fw = (const float*)d_in[3];   // fc_weight [100,2048]
    const float* fb = (const float*)d_in[4];   // fc_bias [100]
    float* out = (float*)d_out;                // [16384,100]

    char* ws = (char*)d_ws;
    float* logits = (float*)ws;                                   // 128 MiB fp32
    const size_t LOGITS_B = (size_t)BROWS * NDIM * 4;             // 134217728
    const size_t XBF_B    = (size_t)BROWS * NDIM * 2;             // 67108864
    const size_t WBF_B    = (size_t)NDIM * NDIM * 2;              // 8388608
    unsigned short* xhi = (unsigned short*)(ws + LOGITS_B);
    unsigned short* xlo = (unsigned short*)(ws + LOGITS_B + XBF_B);
    unsigned short* whi = (unsigned short*)(ws + LOGITS_B + 2 * XBF_B);
    unsigned short* wlo = (unsigned short*)(ws + LOGITS_B + 2 * XBF_B + WBF_B);
    // aliases (dead after gemm1): warped bf16 reuses xlo; fc bf16 reuses wlo
    unsigned short* wbf = xlo;
    unsigned short* fwb = wlo;
    const size_t WS_NEED = LOGITS_B + 2 * XBF_B + 2 * WBF_B;      // 285212672

    if (ws_size >= WS_NEED) {
        const int n4x = BROWS * NDIM / 4;   // 8388608
        const int n4w = NDIM * NDIM / 4;    // 1048576
        prep_kernel<<<(n4x + n4w + 255) / 256, 256, 0, stream>>>(
            (const float4*)x, (const float4*)ww,
            (u16x4*)xhi, (u16x4*)xlo, (u16x4*)whi, (u16x4*)wlo, n4x, n4w);
        gemm1_mfma_fused_kernel<<<dim3(NDIM / 128, BROWS / 128), 256, 0, stream>>>(
            xhi, xlo, whi, wlo, wb, logits);
        warp_bf16_kernel<<<BROWS, 256, 0, stream>>>(xhi, xlo, logits, wbf);
        cvt_bf16_kernel<<<(NCLS * NDIM / 4 + 255) / 256, 256, 0, stream>>>(
            (const float4*)fw, (u16x4*)fwb, NCLS * NDIM / 4);
        gemm2_mfma_kernel<<<BROWS / 64, 256, 0, stream>>>(wbf, fwb, fb, out);
    } else {
        gemm1_kernel<<<dim3(NDIM / 128, BROWS / 128), 256, 0, stream>>>(x, ww, wb, logits);
        warp_kernel_f32<<<BROWS, 256, 0, stream>>>(x, logits);
        gemm2_kernel<<<BROWS / 64, 256, 0, stream>>>(logits, fw, fb, out);
    }
}